// Round 18
// baseline (79.275 us; speedup 1.0000x reference)
//
#include <hip/hip_runtime.h>

#define S_PTS 4096            // sparse point count (fixed by problem)
#define TILE  1024            // points per LDS tile (16 KB)
#define NTILE (S_PTS / TILE)  // 4
#define QPB   16              // queries per block (4 waves x 4 queries)
#define CAP   32              // candidate-list capacity per query

typedef float vf2 __attribute__((ext_vector_type(2)));

// Value-only top-3 insert: b0<=b1<=b2, 3 branchless ops (HW-validated R8/R12/R14).
__device__ __forceinline__ void vins(float v, float& b0, float& b1, float& b2)
{
    const float n0 = fminf(b0, v);
    const float n1 = __builtin_amdgcn_fmed3f(b0, b1, v);
    const float n2 = __builtin_amdgcn_fmed3f(b1, b2, v);
    b0 = n0; b1 = n1; b2 = n2;
}

// Stable top-3 insert by lexicographic (d2, idx) — jax.lax.top_k semantics
// (ties -> lower index). Insertion-order independent. (HW-validated R14.)
__device__ __forceinline__ void insert3_stable(float d, int s,
    float& b0, float& b1, float& b2, int& i0, int& i1, int& i2)
{
    const bool l0 = (d < b0) || (d == b0 && s < i0);
    const bool l1 = (d < b1) || (d == b1 && s < i1);
    const bool l2 = (d < b2) || (d == b2 && s < i2);
    b2 = l1 ? b1 : (l2 ? d : b2);
    i2 = l1 ? i1 : (l2 ? s : i2);
    b1 = l0 ? b0 : (l1 ? d : b1);
    i1 = l0 ? i0 : (l1 ? s : i1);
    b0 = l0 ? d : b0;
    i0 = l0 ? s : i0;
}

// fma-form screen metric e = sn - 2*dot (qn omitted: per-query constant).
// Prescaled LDS tile (-2x,-2y,-2z,sn). Packed -> v_pk_fma_f32.
__device__ __forceinline__ vf2 emetric(const float4 p,
                                       const vf2 X0, const vf2 X1, const vf2 X2)
{
    const vf2 pw = {p.w, p.w};
    vf2 e = pw;
    e += X0 * (vf2){p.x, p.x};
    e += X1 * (vf2){p.y, p.y};
    e += X2 * (vf2){p.z, p.z};
    return e;  // contraction allowed: bound/screen metric only, slack covers
}

// Butterfly-merge COPIES of the per-lane private triples (which are over
// DISJOINT point sets -> merge is the exact top-3-so-far; the private
// triples themselves are never polluted, fixing the R16/R17 double-count
// bug). Returns slackened negated thresholds for the packed screen.
__device__ __forceinline__ void merge_bound(const float* t0, const float* t1,
                                            const float* t2, vf2& NSa, vf2& NSb)
{
    float S[4];
    #pragma unroll
    for (int q = 0; q < 4; ++q) {
        float m0 = t0[q], m1 = t1[q], m2 = t2[q];
        #pragma unroll
        for (int m = 1; m <= 32; m <<= 1) {
            const float o0 = __shfl_xor(m0, m, 64);
            const float o1 = __shfl_xor(m1, m, 64);
            const float o2 = __shfl_xor(m2, m, 64);
            vins(o0, m0, m1, m2);
            vins(o1, m0, m1, m2);
            vins(o2, m0, m1, m2);
        }
        // slack >> |e_fma - e_exact| skew (~1e-5); extras resolved exactly later
        S[q] = m2 + (1e-3f + 1e-4f * fabsf(m2));
    }
    NSa.x = -S[0]; NSa.y = -S[1];
    NSb.x = -S[2]; NSb.y = -S[3];
}

// 256 threads = 4 waves; each wave owns 4 queries scanned by all 64 lanes.
// 16 queries/block, ~18.5 KB LDS -> 8 blocks/CU, grid 2048.
__global__ __launch_bounds__(256, 8)
void upsample_flow_knn3(const float* __restrict__ xyz,         // [B,3,N]
                        const float* __restrict__ sparse_xyz,  // [B,3,S]
                        const float* __restrict__ sparse_flow, // [B,3,S]
                        float* __restrict__ out,               // [B,3,N]
                        int N, int blocks_per_batch)
{
    __shared__ float4 spt[TILE];       // (-2x,-2y,-2z,|s|^2) current tile
    __shared__ int   cand[QPB][CAP];   // candidate indices per query
    __shared__ int   ccnt[QPB];

    const int tid = threadIdx.x;
    const int b   = blockIdx.x / blocks_per_batch;
    const int qb  = blockIdx.x % blocks_per_batch;

    const float* sx = sparse_xyz + (size_t)b * 3 * S_PTS;
    const float* xq = xyz + (size_t)b * 3 * N;

    if (tid < QPB) ccnt[tid] = 0;

    const int g = tid >> 6;   // wave id (0..3)
    const int j = tid & 63;   // lane
    const int q0 = g * 4;     // this wave's first query slot

    // 4 queries per wave: n = qb*16 + g*4 + q (all 64 lanes share them)
    float x0[4], x1[4], x2[4];
    #pragma unroll
    for (int q = 0; q < 4; ++q) {
        const int n = qb * QPB + q0 + q;
        x0[q] = xq[n];
        x1[q] = xq[N + n];
        x2[q] = xq[2 * N + n];
    }
    const vf2 X0a = {x0[0], x0[1]}, X1a = {x1[0], x1[1]}, X2a = {x2[0], x2[1]};
    const vf2 X0b = {x0[2], x0[3]}, X1b = {x1[2], x1[3]}, X2b = {x2[2], x2[3]};

    // private per-lane triples: ONLY this lane's scanned points, never merged
    float t0[4], t1[4], t2[4];
    #pragma unroll
    for (int q = 0; q < 4; ++q) { t0[q] = 3.4e38f; t1[q] = 3.4e38f; t2[q] = 3.4e38f; }

    vf2 NSa = {0.f, 0.f}, NSb = {0.f, 0.f};   // -(S+slack)

#define SCREEN_APPEND(eA, eB, sidx)                                          \
    {                                                                        \
        const vf2 dA = (eA) + NSa;                                           \
        const vf2 dB = (eB) + NSb;                                           \
        if (fminf(fminf(dA.x, dA.y), fminf(dB.x, dB.y)) <= 0.0f) {           \
            if (dA.x <= 0.0f) { const int k = atomicAdd(&ccnt[q0 + 0], 1);   \
                                if (k < CAP) cand[q0 + 0][k] = (sidx); }     \
            if (dA.y <= 0.0f) { const int k = atomicAdd(&ccnt[q0 + 1], 1);   \
                                if (k < CAP) cand[q0 + 1][k] = (sidx); }     \
            if (dB.x <= 0.0f) { const int k = atomicAdd(&ccnt[q0 + 2], 1);   \
                                if (k < CAP) cand[q0 + 2][k] = (sidx); }     \
            if (dB.y <= 0.0f) { const int k = atomicAdd(&ccnt[q0 + 3], 1);   \
                                if (k < CAP) cand[q0 + 3][k] = (sidx); }     \
        }                                                                    \
    }

    // ================= fused scan: bound + screened harvest ================
    for (int t = 0; t < NTILE; ++t) {
        if (t) __syncthreads();  // previous tile fully consumed

        const int sb = t * TILE;
        #pragma unroll
        for (int k = 0; k < TILE / 256; ++k) {
            const int i = k * 256 + tid;
            const float px = sx[sb + i];
            const float py = sx[S_PTS + sb + i];
            const float pz = sx[2 * S_PTS + sb + i];
            const float sn = __fadd_rn(
                __fadd_rn(__fmul_rn(px, px), __fmul_rn(py, py)),
                __fmul_rn(pz, pz));
            spt[i] = make_float4(-2.0f * px, -2.0f * py, -2.0f * pz, sn);
        }
        __syncthreads();

        if (t == 0) {
            // no bound yet: bound-maintain, then merge, then re-screen tile 0
            // while it is still LDS-resident (no end-of-kernel restage).
            #pragma unroll 8
            for (int i = 0; i < TILE / 64; ++i) {
                const float4 p = spt[(i << 6) | j];
                const vf2 eA = emetric(p, X0a, X1a, X2a);
                const vf2 eB = emetric(p, X0b, X1b, X2b);
                vins(eA.x, t0[0], t1[0], t2[0]);
                vins(eA.y, t0[1], t1[1], t2[1]);
                vins(eB.x, t0[2], t1[2], t2[2]);
                vins(eB.y, t0[3], t1[3], t2[3]);
            }
            merge_bound(t0, t1, t2, NSa, NSb);   // S_0 (exact 3rd-of-tile-0)
            #pragma unroll 4
            for (int i = 0; i < TILE / 64; ++i) {
                const int sl = (i << 6) | j;
                const float4 p = spt[sl];
                const vf2 eA = emetric(p, X0a, X1a, X2a);
                const vf2 eB = emetric(p, X0b, X1b, X2b);
                SCREEN_APPEND(eA, eB, sl);
            }
        } else {
            // bound-maintain + screened harvest vs S_{t-1}
            #pragma unroll 4
            for (int i = 0; i < TILE / 64; ++i) {
                const int sl = (i << 6) | j;
                const float4 p = spt[sl];
                const vf2 eA = emetric(p, X0a, X1a, X2a);
                const vf2 eB = emetric(p, X0b, X1b, X2b);
                vins(eA.x, t0[0], t1[0], t2[0]);
                vins(eA.y, t0[1], t1[1], t2[1]);
                vins(eB.x, t0[2], t1[2], t2[2]);
                vins(eB.y, t0[3], t1[3], t2[3]);
                SCREEN_APPEND(eA, eB, sb + sl);
            }
            if (t < NTILE - 1)
                merge_bound(t0, t1, t2, NSa, NSb);   // S_t
        }
    }
    __syncthreads();

    // ======= EXACT SELECT + finalize: one thread per query (tid<16) ========
    // (R14's validated select/finalize; sentinel indices 0 -> never OOB;
    //  a hypothetical short list shows up as absmax failure, not a crash.)
    if (tid < QPB) {
        const int n = qb * QPB + tid;
        if (n < N) {
            const float qx0 = xq[n], qx1 = xq[N + n], qx2 = xq[2 * N + n];
            const float qn = __fadd_rn(
                __fadd_rn(__fmul_rn(qx0, qx0), __fmul_rn(qx1, qx1)),
                __fmul_rn(qx2, qx2));

            float b0 = 3.4e38f, b1 = 3.4e38f, b2 = 3.4e38f;
            int   i0 = 0, i1 = 0, i2 = 0;   // safe sentinels
            const int cnt = min(ccnt[tid], CAP);
            for (int k = 0; k < cnt; ++k) {
                const int s = cand[tid][k];
                const float px = sx[s];
                const float py = sx[S_PTS + s];
                const float pz = sx[2 * S_PTS + s];
                const float sn = __fadd_rn(
                    __fadd_rn(__fmul_rn(px, px), __fmul_rn(py, py)),
                    __fmul_rn(pz, pz));
                // exact reference-rounded d2: (qn - 2*dot) + sn
                const float dot = __fadd_rn(
                    __fadd_rn(__fmul_rn(qx0, px), __fmul_rn(qx1, py)),
                    __fmul_rn(qx2, pz));
                const float d2 = __fadd_rn(
                    __fsub_rn(qn, __fmul_rn(2.0f, dot)), sn);
                insert3_stable(d2, s, b0, b1, b2, i0, i1, i2);
            }

            // weights from direct-diff norm (reference math), gather flow
            const float ax = sx[i0], ay = sx[S_PTS + i0], az = sx[2 * S_PTS + i0];
            const float bx = sx[i1], by = sx[S_PTS + i1], bz = sx[2 * S_PTS + i1];
            const float cx = sx[i2], cy = sx[S_PTS + i2], cz = sx[2 * S_PTS + i2];

            float dx, dy, dz;
            dx = ax - qx0; dy = ay - qx1; dz = az - qx2;
            const float dist0 = fmaxf(sqrtf(dx * dx + dy * dy + dz * dz), 1e-10f);
            dx = bx - qx0; dy = by - qx1; dz = bz - qx2;
            const float dist1 = fmaxf(sqrtf(dx * dx + dy * dy + dz * dz), 1e-10f);
            dx = cx - qx0; dy = cy - qx1; dz = cz - qx2;
            const float dist2 = fmaxf(sqrtf(dx * dx + dy * dy + dz * dz), 1e-10f);

            const float inv0 = 1.0f / dist0;
            const float inv1 = 1.0f / dist1;
            const float inv2 = 1.0f / dist2;
            const float wsum = (inv0 + inv1) + inv2;
            const float w0 = inv0 / wsum;
            const float w1 = inv1 / wsum;
            const float w2 = inv2 / wsum;

            const float* fl = sparse_flow + (size_t)b * 3 * S_PTS;
            float* ob = out + (size_t)b * 3 * N;
            #pragma unroll
            for (int c = 0; c < 3; ++c) {
                const float f0 = fl[c * S_PTS + i0];
                const float f1 = fl[c * S_PTS + i1];
                const float f2 = fl[c * S_PTS + i2];
                ob[c * N + n] = (w0 * f0 + w1 * f1) + w2 * f2;
            }
        }
    }
#undef SCREEN_APPEND
}

extern "C" void kernel_launch(void* const* d_in, const int* in_sizes, int n_in,
                              void* d_out, int out_size, void* d_ws, size_t ws_size,
                              hipStream_t stream)
{
    const float* xyz         = (const float*)d_in[0];
    const float* sparse_xyz  = (const float*)d_in[1];
    const float* sparse_flow = (const float*)d_in[2];
    float* out = (float*)d_out;

    const int B = in_sizes[1] / (3 * S_PTS);          // 2
    const int N = in_sizes[0] / (3 * B);              // 16384
    const int blocks_per_batch = (N + QPB - 1) / QPB; // 1024

    dim3 grid(B * blocks_per_batch);                  // 2048 blocks
    dim3 block(256);
    upsample_flow_knn3<<<grid, block, 0, stream>>>(
        xyz, sparse_xyz, sparse_flow, out, N, blocks_per_batch);
}

// Round 19
// 77.592 us; speedup vs baseline: 1.0217x; 1.0217x over previous
//
#include <hip/hip_runtime.h>

#define S_PTS 4096            // sparse point count (fixed by problem)
#define TILE  1024            // points per LDS tile (16 KB)
#define NTILE (S_PTS / TILE)  // 4
#define QPB   16              // queries per block (4 waves x 4 queries)
#define CAP   32              // candidate-list capacity per query

typedef float vf2 __attribute__((ext_vector_type(2)));

// Value-only top-3 insert: b0<=b1<=b2, 3 branchless ops (HW-validated R8/R12/R14).
__device__ __forceinline__ void vins(float v, float& b0, float& b1, float& b2)
{
    const float n0 = fminf(b0, v);
    const float n1 = __builtin_amdgcn_fmed3f(b0, b1, v);
    const float n2 = __builtin_amdgcn_fmed3f(b1, b2, v);
    b0 = n0; b1 = n1; b2 = n2;
}

// Stable top-3 insert by lexicographic (d2, idx) — jax.lax.top_k semantics
// (ties -> lower index). Insertion-order independent. (HW-validated R14/R18.)
__device__ __forceinline__ void insert3_stable(float d, int s,
    float& b0, float& b1, float& b2, int& i0, int& i1, int& i2)
{
    const bool l0 = (d < b0) || (d == b0 && s < i0);
    const bool l1 = (d < b1) || (d == b1 && s < i1);
    const bool l2 = (d < b2) || (d == b2 && s < i2);
    b2 = l1 ? b1 : (l2 ? d : b2);
    i2 = l1 ? i1 : (l2 ? s : i2);
    b1 = l0 ? b0 : (l1 ? d : b1);
    i1 = l0 ? i0 : (l1 ? s : i1);
    b0 = l0 ? d : b0;
    i0 = l0 ? s : i0;
}

// fma-form screen metric e = sn - 2*dot (qn omitted: per-query constant).
// Prescaled LDS tile (-2x,-2y,-2z,sn). Packed -> v_pk_fma_f32.
__device__ __forceinline__ vf2 emetric(const float4 p,
                                       const vf2 X0, const vf2 X1, const vf2 X2)
{
    const vf2 pw = {p.w, p.w};
    vf2 e = pw;
    e += X0 * (vf2){p.x, p.x};
    e += X1 * (vf2){p.y, p.y};
    e += X2 * (vf2){p.z, p.z};
    return e;  // contraction allowed: bound/screen metric only, slack covers
}

// 256 threads = 4 waves; each wave owns 4 queries scanned by all 64 lanes.
// 16 queries/block, ~18.5 KB LDS -> 8 blocks/CU, grid 2048.
__global__ __launch_bounds__(256, 8)
void upsample_flow_knn3(const float* __restrict__ xyz,         // [B,3,N]
                        const float* __restrict__ sparse_xyz,  // [B,3,S]
                        const float* __restrict__ sparse_flow, // [B,3,S]
                        float* __restrict__ out,               // [B,3,N]
                        int N, int blocks_per_batch)
{
    __shared__ float4 spt[TILE];       // (-2x,-2y,-2z,|s|^2) current tile
    __shared__ int   cand[QPB][CAP];   // candidate indices per query
    __shared__ int   ccnt[QPB];

    const int tid = threadIdx.x;
    const int b   = blockIdx.x / blocks_per_batch;
    const int qb  = blockIdx.x % blocks_per_batch;

    const float* sx = sparse_xyz + (size_t)b * 3 * S_PTS;
    const float* xq = xyz + (size_t)b * 3 * N;

    if (tid < QPB) ccnt[tid] = 0;

    const int g = tid >> 6;   // wave id (0..3)
    const int j = tid & 63;   // lane
    const int q0 = g * 4;     // this wave's first query slot

    // 4 queries per wave: n = qb*16 + g*4 + q (all 64 lanes share them)
    float x0[4], x1[4], x2[4];
    #pragma unroll
    for (int q = 0; q < 4; ++q) {
        const int n = qb * QPB + q0 + q;
        x0[q] = xq[n];
        x1[q] = xq[N + n];
        x2[q] = xq[2 * N + n];
    }
    const vf2 X0a = {x0[0], x0[1]}, X1a = {x1[0], x1[1]}, X2a = {x2[0], x2[1]};
    const vf2 X0b = {x0[2], x0[3]}, X1b = {x1[2], x1[3]}, X2b = {x2[2], x2[3]};

    // private per-lane triples: ONLY this lane's scanned points, never merged.
    // (Kept as individually-named scalars + macro merge — NOT function-call
    //  args — so nothing is address-taken and all state stays in VGPRs;
    //  R18's 55 MB/dispatch scratch spill came from passing these as float*.)
    float t0[4], t1[4], t2[4];
    #pragma unroll
    for (int q = 0; q < 4; ++q) { t0[q] = 3.4e38f; t1[q] = 3.4e38f; t2[q] = 3.4e38f; }

    vf2 NSa = {0.f, 0.f}, NSb = {0.f, 0.f};   // -(S+slack)

// Butterfly-merge COPIES of the private triples (disjoint point sets ->
// merged triple = exact top-3-so-far; privates stay unpolluted, which is
// the R17 double-count fix). Compile-time indices only -> pure VGPR.
#define MERGE_BOUND()                                                        \
    {                                                                        \
        float S_[4];                                                         \
        _Pragma("unroll")                                                    \
        for (int q = 0; q < 4; ++q) {                                        \
            float m0 = t0[q], m1 = t1[q], m2 = t2[q];                        \
            _Pragma("unroll")                                                \
            for (int mm = 1; mm <= 32; mm <<= 1) {                           \
                const float o0 = __shfl_xor(m0, mm, 64);                     \
                const float o1 = __shfl_xor(m1, mm, 64);                     \
                const float o2 = __shfl_xor(m2, mm, 64);                     \
                vins(o0, m0, m1, m2);                                        \
                vins(o1, m0, m1, m2);                                        \
                vins(o2, m0, m1, m2);                                        \
            }                                                                \
            S_[q] = m2 + (1e-3f + 1e-4f * fabsf(m2));                        \
        }                                                                    \
        NSa.x = -S_[0]; NSa.y = -S_[1];                                      \
        NSb.x = -S_[2]; NSb.y = -S_[3];                                      \
    }

#define SCREEN_APPEND(eA, eB, sidx)                                          \
    {                                                                        \
        const vf2 dA = (eA) + NSa;                                           \
        const vf2 dB = (eB) + NSb;                                           \
        if (fminf(fminf(dA.x, dA.y), fminf(dB.x, dB.y)) <= 0.0f) {           \
            if (dA.x <= 0.0f) { const int k = atomicAdd(&ccnt[q0 + 0], 1);   \
                                if (k < CAP) cand[q0 + 0][k] = (sidx); }     \
            if (dA.y <= 0.0f) { const int k = atomicAdd(&ccnt[q0 + 1], 1);   \
                                if (k < CAP) cand[q0 + 1][k] = (sidx); }     \
            if (dB.x <= 0.0f) { const int k = atomicAdd(&ccnt[q0 + 2], 1);   \
                                if (k < CAP) cand[q0 + 2][k] = (sidx); }     \
            if (dB.y <= 0.0f) { const int k = atomicAdd(&ccnt[q0 + 3], 1);   \
                                if (k < CAP) cand[q0 + 3][k] = (sidx); }     \
        }                                                                    \
    }

    // ================= fused scan: bound + screened harvest ================
    for (int t = 0; t < NTILE; ++t) {
        if (t) __syncthreads();  // previous tile fully consumed

        const int sb = t * TILE;
        #pragma unroll
        for (int k = 0; k < TILE / 256; ++k) {
            const int i = k * 256 + tid;
            const float px = sx[sb + i];
            const float py = sx[S_PTS + sb + i];
            const float pz = sx[2 * S_PTS + sb + i];
            const float sn = __fadd_rn(
                __fadd_rn(__fmul_rn(px, px), __fmul_rn(py, py)),
                __fmul_rn(pz, pz));
            spt[i] = make_float4(-2.0f * px, -2.0f * py, -2.0f * pz, sn);
        }
        __syncthreads();

        if (t == 0) {
            // no bound yet: bound-maintain, merge, then re-screen tile 0
            // while it is still LDS-resident.
            #pragma unroll 8
            for (int i = 0; i < TILE / 64; ++i) {
                const float4 p = spt[(i << 6) | j];
                const vf2 eA = emetric(p, X0a, X1a, X2a);
                const vf2 eB = emetric(p, X0b, X1b, X2b);
                vins(eA.x, t0[0], t1[0], t2[0]);
                vins(eA.y, t0[1], t1[1], t2[1]);
                vins(eB.x, t0[2], t1[2], t2[2]);
                vins(eB.y, t0[3], t1[3], t2[3]);
            }
            MERGE_BOUND();   // S_0 = exact 3rd-of-tile-0
            #pragma unroll 4
            for (int i = 0; i < TILE / 64; ++i) {
                const int sl = (i << 6) | j;
                const float4 p = spt[sl];
                const vf2 eA = emetric(p, X0a, X1a, X2a);
                const vf2 eB = emetric(p, X0b, X1b, X2b);
                SCREEN_APPEND(eA, eB, sl);
            }
        } else {
            // bound-maintain + screened harvest vs S_{t-1}
            #pragma unroll 4
            for (int i = 0; i < TILE / 64; ++i) {
                const int sl = (i << 6) | j;
                const float4 p = spt[sl];
                const vf2 eA = emetric(p, X0a, X1a, X2a);
                const vf2 eB = emetric(p, X0b, X1b, X2b);
                vins(eA.x, t0[0], t1[0], t2[0]);
                vins(eA.y, t0[1], t1[1], t2[1]);
                vins(eB.x, t0[2], t1[2], t2[2]);
                vins(eB.y, t0[3], t1[3], t2[3]);
                SCREEN_APPEND(eA, eB, sb + sl);
            }
            if (t < NTILE - 1)
                MERGE_BOUND();   // S_t
        }
    }
    __syncthreads();

    // ======= EXACT SELECT + finalize: one thread per query (tid<16) ========
    // (R14/R18-validated; sentinel indices 0 -> never OOB.)
    if (tid < QPB) {
        const int n = qb * QPB + tid;
        if (n < N) {
            const float qx0 = xq[n], qx1 = xq[N + n], qx2 = xq[2 * N + n];
            const float qn = __fadd_rn(
                __fadd_rn(__fmul_rn(qx0, qx0), __fmul_rn(qx1, qx1)),
                __fmul_rn(qx2, qx2));

            float b0 = 3.4e38f, b1 = 3.4e38f, b2 = 3.4e38f;
            int   i0 = 0, i1 = 0, i2 = 0;   // safe sentinels
            const int cnt = min(ccnt[tid], CAP);
            for (int k = 0; k < cnt; ++k) {
                const int s = cand[tid][k];
                const float px = sx[s];
                const float py = sx[S_PTS + s];
                const float pz = sx[2 * S_PTS + s];
                const float sn = __fadd_rn(
                    __fadd_rn(__fmul_rn(px, px), __fmul_rn(py, py)),
                    __fmul_rn(pz, pz));
                // exact reference-rounded d2: (qn - 2*dot) + sn
                const float dot = __fadd_rn(
                    __fadd_rn(__fmul_rn(qx0, px), __fmul_rn(qx1, py)),
                    __fmul_rn(qx2, pz));
                const float d2 = __fadd_rn(
                    __fsub_rn(qn, __fmul_rn(2.0f, dot)), sn);
                insert3_stable(d2, s, b0, b1, b2, i0, i1, i2);
            }

            // weights from direct-diff norm (reference math), gather flow
            const float ax = sx[i0], ay = sx[S_PTS + i0], az = sx[2 * S_PTS + i0];
            const float bx = sx[i1], by = sx[S_PTS + i1], bz = sx[2 * S_PTS + i1];
            const float cx = sx[i2], cy = sx[S_PTS + i2], cz = sx[2 * S_PTS + i2];

            float dx, dy, dz;
            dx = ax - qx0; dy = ay - qx1; dz = az - qx2;
            const float dist0 = fmaxf(sqrtf(dx * dx + dy * dy + dz * dz), 1e-10f);
            dx = bx - qx0; dy = by - qx1; dz = bz - qx2;
            const float dist1 = fmaxf(sqrtf(dx * dx + dy * dy + dz * dz), 1e-10f);
            dx = cx - qx0; dy = cy - qx1; dz = cz - qx2;
            const float dist2 = fmaxf(sqrtf(dx * dx + dy * dy + dz * dz), 1e-10f);

            const float inv0 = 1.0f / dist0;
            const float inv1 = 1.0f / dist1;
            const float inv2 = 1.0f / dist2;
            const float wsum = (inv0 + inv1) + inv2;
            const float w0 = inv0 / wsum;
            const float w1 = inv1 / wsum;
            const float w2 = inv2 / wsum;

            const float* fl = sparse_flow + (size_t)b * 3 * S_PTS;
            float* ob = out + (size_t)b * 3 * N;
            #pragma unroll
            for (int c = 0; c < 3; ++c) {
                const float f0 = fl[c * S_PTS + i0];
                const float f1 = fl[c * S_PTS + i1];
                const float f2 = fl[c * S_PTS + i2];
                ob[c * N + n] = (w0 * f0 + w1 * f1) + w2 * f2;
            }
        }
    }
#undef SCREEN_APPEND
#undef MERGE_BOUND
}

extern "C" void kernel_launch(void* const* d_in, const int* in_sizes, int n_in,
                              void* d_out, int out_size, void* d_ws, size_t ws_size,
                              hipStream_t stream)
{
    const float* xyz         = (const float*)d_in[0];
    const float* sparse_xyz  = (const float*)d_in[1];
    const float* sparse_flow = (const float*)d_in[2];
    float* out = (float*)d_out;

    const int B = in_sizes[1] / (3 * S_PTS);          // 2
    const int N = in_sizes[0] / (3 * B);              // 16384
    const int blocks_per_batch = (N + QPB - 1) / QPB; // 1024

    dim3 grid(B * blocks_per_batch);                  // 2048 blocks
    dim3 block(256);
    upsample_flow_knn3<<<grid, block, 0, stream>>>(
        xyz, sparse_xyz, sparse_flow, out, N, blocks_per_batch);
}

// Round 20
// 56.587 us; speedup vs baseline: 1.4009x; 1.3712x over previous
//
#include <hip/hip_runtime.h>

#define S_PTS 4096            // sparse point count (fixed by problem)
#define TILE  2048            // points per LDS tile (32 KB)
#define NTILE (S_PTS / TILE)  // 2
#define QPB   16              // queries per block (4 waves x 4 queries)
#define CAP   32              // candidate-list capacity per query

typedef float vf2 __attribute__((ext_vector_type(2)));

// Value-only top-3 insert: b0<=b1<=b2, 3 branchless ops (HW-validated R8/R12/R14).
__device__ __forceinline__ void vins(float v, float& b0, float& b1, float& b2)
{
    const float n0 = fminf(b0, v);
    const float n1 = __builtin_amdgcn_fmed3f(b0, b1, v);
    const float n2 = __builtin_amdgcn_fmed3f(b1, b2, v);
    b0 = n0; b1 = n1; b2 = n2;
}

// Stable top-3 insert by lexicographic (d2, idx) — jax.lax.top_k semantics
// (ties -> lower index). Insertion-order independent. (HW-validated R14/R18/R19.)
__device__ __forceinline__ void insert3_stable(float d, int s,
    float& b0, float& b1, float& b2, int& i0, int& i1, int& i2)
{
    const bool l0 = (d < b0) || (d == b0 && s < i0);
    const bool l1 = (d < b1) || (d == b1 && s < i1);
    const bool l2 = (d < b2) || (d == b2 && s < i2);
    b2 = l1 ? b1 : (l2 ? d : b2);
    i2 = l1 ? i1 : (l2 ? s : i2);
    b1 = l0 ? b0 : (l1 ? d : b1);
    i1 = l0 ? i0 : (l1 ? s : i1);
    b0 = l0 ? d : b0;
    i0 = l0 ? s : i0;
}

// fma-form screen metric e = sn - 2*dot (qn omitted: per-query constant).
// Prescaled LDS tile (-2x,-2y,-2z,sn). Packed -> v_pk_fma_f32.
__device__ __forceinline__ vf2 emetric(const float4 p,
                                       const vf2 X0, const vf2 X1, const vf2 X2)
{
    const vf2 pw = {p.w, p.w};
    vf2 e = pw;
    e += X0 * (vf2){p.x, p.x};
    e += X1 * (vf2){p.y, p.y};
    e += X2 * (vf2){p.z, p.z};
    return e;  // contraction allowed: bound/screen metric only, slack covers
}

// 256 threads = 4 waves; each wave owns 4 queries scanned by all 64 lanes.
// 16 queries/block, ~34.9 KB LDS -> 4 blocks/CU (launch_bounds(256,4) ->
// 128-VGPR budget: removes the R18/R19 spill, whose 55 MB/dispatch scratch
// round-trip came from the 64-VGPR cap at (256,8) + in-loop merge pressure).
__global__ __launch_bounds__(256, 4)
void upsample_flow_knn3(const float* __restrict__ xyz,         // [B,3,N]
                        const float* __restrict__ sparse_xyz,  // [B,3,S]
                        const float* __restrict__ sparse_flow, // [B,3,S]
                        float* __restrict__ out,               // [B,3,N]
                        int N, int blocks_per_batch)
{
    __shared__ float4 spt[TILE];       // (-2x,-2y,-2z,|s|^2) current tile
    __shared__ int   cand[QPB][CAP];   // candidate indices per query
    __shared__ int   ccnt[QPB];

    const int tid = threadIdx.x;
    const int b   = blockIdx.x / blocks_per_batch;
    const int qb  = blockIdx.x % blocks_per_batch;

    const float* sx = sparse_xyz + (size_t)b * 3 * S_PTS;
    const float* xq = xyz + (size_t)b * 3 * N;

    if (tid < QPB) ccnt[tid] = 0;

    const int g = tid >> 6;   // wave id (0..3)
    const int j = tid & 63;   // lane
    const int q0 = g * 4;     // this wave's first query slot

    // 4 queries per wave: n = qb*16 + g*4 + q (all 64 lanes share them)
    float x0[4], x1[4], x2[4];
    #pragma unroll
    for (int q = 0; q < 4; ++q) {
        const int n = qb * QPB + q0 + q;
        x0[q] = xq[n];
        x1[q] = xq[N + n];
        x2[q] = xq[2 * N + n];
    }
    const vf2 X0a = {x0[0], x0[1]}, X1a = {x1[0], x1[1]}, X2a = {x2[0], x2[1]};
    const vf2 X0b = {x0[2], x0[3]}, X1b = {x1[2], x1[3]}, X2b = {x2[2], x2[3]};

    // private per-lane triples over DISJOINT point subsets (never merged
    // in place -> no double-count; R17 bug fix kept)
    float t0[4], t1[4], t2[4];
    #pragma unroll
    for (int q = 0; q < 4; ++q) { t0[q] = 3.4e38f; t1[q] = 3.4e38f; t2[q] = 3.4e38f; }

    vf2 NSa = {0.f, 0.f}, NSb = {0.f, 0.f};   // -(S+slack)

// Butterfly-merge COPIES of the private triples (disjoint sets -> merged
// triple = exact top-3-so-far). Runs ONCE per kernel (after tile 0).
#define MERGE_BOUND()                                                        \
    {                                                                        \
        float S_[4];                                                         \
        _Pragma("unroll")                                                    \
        for (int q = 0; q < 4; ++q) {                                        \
            float m0 = t0[q], m1 = t1[q], m2 = t2[q];                        \
            _Pragma("unroll")                                                \
            for (int mm = 1; mm <= 32; mm <<= 1) {                           \
                const float o0 = __shfl_xor(m0, mm, 64);                     \
                const float o1 = __shfl_xor(m1, mm, 64);                     \
                const float o2 = __shfl_xor(m2, mm, 64);                     \
                vins(o0, m0, m1, m2);                                        \
                vins(o1, m0, m1, m2);                                        \
                vins(o2, m0, m1, m2);                                        \
            }                                                                \
            S_[q] = m2 + (1e-3f + 1e-4f * fabsf(m2));                        \
        }                                                                    \
        NSa.x = -S_[0]; NSa.y = -S_[1];                                      \
        NSb.x = -S_[2]; NSb.y = -S_[3];                                      \
    }

#define SCREEN_APPEND(eA, eB, sidx)                                          \
    {                                                                        \
        const vf2 dA = (eA) + NSa;                                           \
        const vf2 dB = (eB) + NSb;                                           \
        if (fminf(fminf(dA.x, dA.y), fminf(dB.x, dB.y)) <= 0.0f) {           \
            if (dA.x <= 0.0f) { const int k = atomicAdd(&ccnt[q0 + 0], 1);   \
                                if (k < CAP) cand[q0 + 0][k] = (sidx); }     \
            if (dA.y <= 0.0f) { const int k = atomicAdd(&ccnt[q0 + 1], 1);   \
                                if (k < CAP) cand[q0 + 1][k] = (sidx); }     \
            if (dB.x <= 0.0f) { const int k = atomicAdd(&ccnt[q0 + 2], 1);   \
                                if (k < CAP) cand[q0 + 2][k] = (sidx); }     \
            if (dB.y <= 0.0f) { const int k = atomicAdd(&ccnt[q0 + 3], 1);   \
                                if (k < CAP) cand[q0 + 3][k] = (sidx); }     \
        }                                                                    \
    }

    // ================= fused scan: bound + screened harvest ================
    for (int t = 0; t < NTILE; ++t) {
        if (t) __syncthreads();  // previous tile fully consumed

        const int sb = t * TILE;
        #pragma unroll
        for (int k = 0; k < TILE / 256; ++k) {
            const int i = k * 256 + tid;
            const float px = sx[sb + i];
            const float py = sx[S_PTS + sb + i];
            const float pz = sx[2 * S_PTS + sb + i];
            const float sn = __fadd_rn(
                __fadd_rn(__fmul_rn(px, px), __fmul_rn(py, py)),
                __fmul_rn(pz, pz));
            spt[i] = make_float4(-2.0f * px, -2.0f * py, -2.0f * pz, sn);
        }
        __syncthreads();

        if (t == 0) {
            // bound-maintain over tile 0, merge once, re-screen tile 0
            // while it is still LDS-resident.
            #pragma unroll 8
            for (int i = 0; i < TILE / 64; ++i) {
                const float4 p = spt[(i << 6) | j];
                const vf2 eA = emetric(p, X0a, X1a, X2a);
                const vf2 eB = emetric(p, X0b, X1b, X2b);
                vins(eA.x, t0[0], t1[0], t2[0]);
                vins(eA.y, t0[1], t1[1], t2[1]);
                vins(eB.x, t0[2], t1[2], t2[2]);
                vins(eB.y, t0[3], t1[3], t2[3]);
            }
            MERGE_BOUND();   // S_0 = exact 3rd-of-tile-0 (+slack)
            #pragma unroll 4
            for (int i = 0; i < TILE / 64; ++i) {
                const int sl = (i << 6) | j;
                const float4 p = spt[sl];
                const vf2 eA = emetric(p, X0a, X1a, X2a);
                const vf2 eB = emetric(p, X0b, X1b, X2b);
                SCREEN_APPEND(eA, eB, sl);
            }
        } else {
            // final tile: screened harvest vs S_0 (no further merge needed)
            #pragma unroll 4
            for (int i = 0; i < TILE / 64; ++i) {
                const int sl = (i << 6) | j;
                const float4 p = spt[sl];
                const vf2 eA = emetric(p, X0a, X1a, X2a);
                const vf2 eB = emetric(p, X0b, X1b, X2b);
                SCREEN_APPEND(eA, eB, sb + sl);
            }
        }
    }
    __syncthreads();

    // ======= EXACT SELECT + finalize: one thread per query (tid<16) ========
    // (R14/R18/R19-validated; sentinel indices 0 -> never OOB.)
    if (tid < QPB) {
        const int n = qb * QPB + tid;
        if (n < N) {
            const float qx0 = xq[n], qx1 = xq[N + n], qx2 = xq[2 * N + n];
            const float qn = __fadd_rn(
                __fadd_rn(__fmul_rn(qx0, qx0), __fmul_rn(qx1, qx1)),
                __fmul_rn(qx2, qx2));

            float b0 = 3.4e38f, b1 = 3.4e38f, b2 = 3.4e38f;
            int   i0 = 0, i1 = 0, i2 = 0;   // safe sentinels
            const int cnt = min(ccnt[tid], CAP);
            for (int k = 0; k < cnt; ++k) {
                const int s = cand[tid][k];
                const float px = sx[s];
                const float py = sx[S_PTS + s];
                const float pz = sx[2 * S_PTS + s];
                const float sn = __fadd_rn(
                    __fadd_rn(__fmul_rn(px, px), __fmul_rn(py, py)),
                    __fmul_rn(pz, pz));
                // exact reference-rounded d2: (qn - 2*dot) + sn
                const float dot = __fadd_rn(
                    __fadd_rn(__fmul_rn(qx0, px), __fmul_rn(qx1, py)),
                    __fmul_rn(qx2, pz));
                const float d2 = __fadd_rn(
                    __fsub_rn(qn, __fmul_rn(2.0f, dot)), sn);
                insert3_stable(d2, s, b0, b1, b2, i0, i1, i2);
            }

            // weights from direct-diff norm (reference math), gather flow
            const float ax = sx[i0], ay = sx[S_PTS + i0], az = sx[2 * S_PTS + i0];
            const float bx = sx[i1], by = sx[S_PTS + i1], bz = sx[2 * S_PTS + i1];
            const float cx = sx[i2], cy = sx[S_PTS + i2], cz = sx[2 * S_PTS + i2];

            float dx, dy, dz;
            dx = ax - qx0; dy = ay - qx1; dz = az - qx2;
            const float dist0 = fmaxf(sqrtf(dx * dx + dy * dy + dz * dz), 1e-10f);
            dx = bx - qx0; dy = by - qx1; dz = bz - qx2;
            const float dist1 = fmaxf(sqrtf(dx * dx + dy * dy + dz * dz), 1e-10f);
            dx = cx - qx0; dy = cy - qx1; dz = cz - qx2;
            const float dist2 = fmaxf(sqrtf(dx * dx + dy * dy + dz * dz), 1e-10f);

            const float inv0 = 1.0f / dist0;
            const float inv1 = 1.0f / dist1;
            const float inv2 = 1.0f / dist2;
            const float wsum = (inv0 + inv1) + inv2;
            const float w0 = inv0 / wsum;
            const float w1 = inv1 / wsum;
            const float w2 = inv2 / wsum;

            const float* fl = sparse_flow + (size_t)b * 3 * S_PTS;
            float* ob = out + (size_t)b * 3 * N;
            #pragma unroll
            for (int c = 0; c < 3; ++c) {
                const float f0 = fl[c * S_PTS + i0];
                const float f1 = fl[c * S_PTS + i1];
                const float f2 = fl[c * S_PTS + i2];
                ob[c * N + n] = (w0 * f0 + w1 * f1) + w2 * f2;
            }
        }
    }
#undef SCREEN_APPEND
#undef MERGE_BOUND
}

extern "C" void kernel_launch(void* const* d_in, const int* in_sizes, int n_in,
                              void* d_out, int out_size, void* d_ws, size_t ws_size,
                              hipStream_t stream)
{
    const float* xyz         = (const float*)d_in[0];
    const float* sparse_xyz  = (const float*)d_in[1];
    const float* sparse_flow = (const float*)d_in[2];
    float* out = (float*)d_out;

    const int B = in_sizes[1] / (3 * S_PTS);          // 2
    const int N = in_sizes[0] / (3 * B);              // 16384
    const int blocks_per_batch = (N + QPB - 1) / QPB; // 1024

    dim3 grid(B * blocks_per_batch);                  // 2048 blocks
    dim3 block(256);
    upsample_flow_knn3<<<grid, block, 0, stream>>>(
        xyz, sparse_xyz, sparse_flow, out, N, blocks_per_batch);
}

// Round 21
// 56.417 us; speedup vs baseline: 1.4052x; 1.0030x over previous
//
#include <hip/hip_runtime.h>

#define S_PTS 4096            // sparse point count (fixed by problem)
#define TILE  2048            // points per LDS tile (32 KB)
#define NTILE (S_PTS / TILE)  // 2
#define QPB   16              // queries per block (4 waves x 4 queries)
#define CAP   32              // candidate-list capacity per query

typedef float vf2 __attribute__((ext_vector_type(2)));

// Value-only top-3 insert: b0<=b1<=b2, 3 branchless ops (HW-validated R8/R12/R14).
__device__ __forceinline__ void vins(float v, float& b0, float& b1, float& b2)
{
    const float n0 = fminf(b0, v);
    const float n1 = __builtin_amdgcn_fmed3f(b0, b1, v);
    const float n2 = __builtin_amdgcn_fmed3f(b1, b2, v);
    b0 = n0; b1 = n1; b2 = n2;
}

// Stable top-3 insert by lexicographic (d2, idx) — jax.lax.top_k semantics
// (ties -> lower index). Insertion-order independent. (HW-validated R14/R18/R19.)
__device__ __forceinline__ void insert3_stable(float d, int s,
    float& b0, float& b1, float& b2, int& i0, int& i1, int& i2)
{
    const bool l0 = (d < b0) || (d == b0 && s < i0);
    const bool l1 = (d < b1) || (d == b1 && s < i1);
    const bool l2 = (d < b2) || (d == b2 && s < i2);
    b2 = l1 ? b1 : (l2 ? d : b2);
    i2 = l1 ? i1 : (l2 ? s : i2);
    b1 = l0 ? b0 : (l1 ? d : b1);
    i1 = l0 ? i0 : (l1 ? s : i1);
    b0 = l0 ? d : b0;
    i0 = l0 ? s : i0;
}

// fma-form screen metric e = sn - 2*dot (qn omitted: per-query constant).
// Prescaled LDS tile (-2x,-2y,-2z,sn). Packed -> v_pk_fma_f32.
__device__ __forceinline__ vf2 emetric(const float4 p,
                                       const vf2 X0, const vf2 X1, const vf2 X2)
{
    const vf2 pw = {p.w, p.w};
    vf2 e = pw;
    e += X0 * (vf2){p.x, p.x};
    e += X1 * (vf2){p.y, p.y};
    e += X2 * (vf2){p.z, p.z};
    return e;  // contraction allowed: bound/screen metric only, slack covers
}

// 256 threads = 4 waves; each wave owns 4 queries scanned by all 64 lanes.
// 16 queries/block, ~34.9 KB LDS -> 4 blocks/CU (launch_bounds(256,4) ->
// 128-VGPR budget: removes the R18/R19 spill, whose 55 MB/dispatch scratch
// round-trip came from the 64-VGPR cap at (256,8) + in-loop merge pressure).
__global__ __launch_bounds__(256, 4)
void upsample_flow_knn3(const float* __restrict__ xyz,         // [B,3,N]
                        const float* __restrict__ sparse_xyz,  // [B,3,S]
                        const float* __restrict__ sparse_flow, // [B,3,S]
                        float* __restrict__ out,               // [B,3,N]
                        int N, int blocks_per_batch)
{
    __shared__ float4 spt[TILE];       // (-2x,-2y,-2z,|s|^2) current tile
    __shared__ int   cand[QPB][CAP];   // candidate indices per query
    __shared__ int   ccnt[QPB];

    const int tid = threadIdx.x;
    const int b   = blockIdx.x / blocks_per_batch;
    const int qb  = blockIdx.x % blocks_per_batch;

    const float* sx = sparse_xyz + (size_t)b * 3 * S_PTS;
    const float* xq = xyz + (size_t)b * 3 * N;

    if (tid < QPB) ccnt[tid] = 0;

    const int g = tid >> 6;   // wave id (0..3)
    const int j = tid & 63;   // lane
    const int q0 = g * 4;     // this wave's first query slot

    // 4 queries per wave: n = qb*16 + g*4 + q (all 64 lanes share them)
    float x0[4], x1[4], x2[4];
    #pragma unroll
    for (int q = 0; q < 4; ++q) {
        const int n = qb * QPB + q0 + q;
        x0[q] = xq[n];
        x1[q] = xq[N + n];
        x2[q] = xq[2 * N + n];
    }
    const vf2 X0a = {x0[0], x0[1]}, X1a = {x1[0], x1[1]}, X2a = {x2[0], x2[1]};
    const vf2 X0b = {x0[2], x0[3]}, X1b = {x1[2], x1[3]}, X2b = {x2[2], x2[3]};

    // private per-lane triples over DISJOINT point subsets (never merged
    // in place -> no double-count; R17 bug fix kept)
    float t0[4], t1[4], t2[4];
    #pragma unroll
    for (int q = 0; q < 4; ++q) { t0[q] = 3.4e38f; t1[q] = 3.4e38f; t2[q] = 3.4e38f; }

    vf2 NSa = {0.f, 0.f}, NSb = {0.f, 0.f};   // -(S+slack)

// Butterfly-merge COPIES of the private triples (disjoint sets -> merged
// triple = exact top-3-so-far). Runs ONCE per kernel (after tile 0).
#define MERGE_BOUND()                                                        \
    {                                                                        \
        float S_[4];                                                         \
        _Pragma("unroll")                                                    \
        for (int q = 0; q < 4; ++q) {                                        \
            float m0 = t0[q], m1 = t1[q], m2 = t2[q];                        \
            _Pragma("unroll")                                                \
            for (int mm = 1; mm <= 32; mm <<= 1) {                           \
                const float o0 = __shfl_xor(m0, mm, 64);                     \
                const float o1 = __shfl_xor(m1, mm, 64);                     \
                const float o2 = __shfl_xor(m2, mm, 64);                     \
                vins(o0, m0, m1, m2);                                        \
                vins(o1, m0, m1, m2);                                        \
                vins(o2, m0, m1, m2);                                        \
            }                                                                \
            S_[q] = m2 + (1e-3f + 1e-4f * fabsf(m2));                        \
        }                                                                    \
        NSa.x = -S_[0]; NSa.y = -S_[1];                                      \
        NSb.x = -S_[2]; NSb.y = -S_[3];                                      \
    }

#define SCREEN_APPEND(eA, eB, sidx)                                          \
    {                                                                        \
        const vf2 dA = (eA) + NSa;                                           \
        const vf2 dB = (eB) + NSb;                                           \
        if (fminf(fminf(dA.x, dA.y), fminf(dB.x, dB.y)) <= 0.0f) {           \
            if (dA.x <= 0.0f) { const int k = atomicAdd(&ccnt[q0 + 0], 1);   \
                                if (k < CAP) cand[q0 + 0][k] = (sidx); }     \
            if (dA.y <= 0.0f) { const int k = atomicAdd(&ccnt[q0 + 1], 1);   \
                                if (k < CAP) cand[q0 + 1][k] = (sidx); }     \
            if (dB.x <= 0.0f) { const int k = atomicAdd(&ccnt[q0 + 2], 1);   \
                                if (k < CAP) cand[q0 + 2][k] = (sidx); }     \
            if (dB.y <= 0.0f) { const int k = atomicAdd(&ccnt[q0 + 3], 1);   \
                                if (k < CAP) cand[q0 + 3][k] = (sidx); }     \
        }                                                                    \
    }

    // ================= fused scan: bound + screened harvest ================
    for (int t = 0; t < NTILE; ++t) {
        if (t) __syncthreads();  // previous tile fully consumed

        const int sb = t * TILE;
        #pragma unroll
        for (int k = 0; k < TILE / 256; ++k) {
            const int i = k * 256 + tid;
            const float px = sx[sb + i];
            const float py = sx[S_PTS + sb + i];
            const float pz = sx[2 * S_PTS + sb + i];
            const float sn = __fadd_rn(
                __fadd_rn(__fmul_rn(px, px), __fmul_rn(py, py)),
                __fmul_rn(pz, pz));
            spt[i] = make_float4(-2.0f * px, -2.0f * py, -2.0f * pz, sn);
        }
        __syncthreads();

        if (t == 0) {
            // bound-maintain over tile 0, merge once, re-screen tile 0
            // while it is still LDS-resident.
            #pragma unroll 8
            for (int i = 0; i < TILE / 64; ++i) {
                const float4 p = spt[(i << 6) | j];
                const vf2 eA = emetric(p, X0a, X1a, X2a);
                const vf2 eB = emetric(p, X0b, X1b, X2b);
                vins(eA.x, t0[0], t1[0], t2[0]);
                vins(eA.y, t0[1], t1[1], t2[1]);
                vins(eB.x, t0[2], t1[2], t2[2]);
                vins(eB.y, t0[3], t1[3], t2[3]);
            }
            MERGE_BOUND();   // S_0 = exact 3rd-of-tile-0 (+slack)
            #pragma unroll 4
            for (int i = 0; i < TILE / 64; ++i) {
                const int sl = (i << 6) | j;
                const float4 p = spt[sl];
                const vf2 eA = emetric(p, X0a, X1a, X2a);
                const vf2 eB = emetric(p, X0b, X1b, X2b);
                SCREEN_APPEND(eA, eB, sl);
            }
        } else {
            // final tile: screened harvest vs S_0 (no further merge needed)
            #pragma unroll 4
            for (int i = 0; i < TILE / 64; ++i) {
                const int sl = (i << 6) | j;
                const float4 p = spt[sl];
                const vf2 eA = emetric(p, X0a, X1a, X2a);
                const vf2 eB = emetric(p, X0b, X1b, X2b);
                SCREEN_APPEND(eA, eB, sb + sl);
            }
        }
    }
    __syncthreads();

    // ======= EXACT SELECT + finalize: one thread per query (tid<16) ========
    // (R14/R18/R19-validated; sentinel indices 0 -> never OOB.)
    if (tid < QPB) {
        const int n = qb * QPB + tid;
        if (n < N) {
            const float qx0 = xq[n], qx1 = xq[N + n], qx2 = xq[2 * N + n];
            const float qn = __fadd_rn(
                __fadd_rn(__fmul_rn(qx0, qx0), __fmul_rn(qx1, qx1)),
                __fmul_rn(qx2, qx2));

            float b0 = 3.4e38f, b1 = 3.4e38f, b2 = 3.4e38f;
            int   i0 = 0, i1 = 0, i2 = 0;   // safe sentinels
            const int cnt = min(ccnt[tid], CAP);
            for (int k = 0; k < cnt; ++k) {
                const int s = cand[tid][k];
                const float px = sx[s];
                const float py = sx[S_PTS + s];
                const float pz = sx[2 * S_PTS + s];
                const float sn = __fadd_rn(
                    __fadd_rn(__fmul_rn(px, px), __fmul_rn(py, py)),
                    __fmul_rn(pz, pz));
                // exact reference-rounded d2: (qn - 2*dot) + sn
                const float dot = __fadd_rn(
                    __fadd_rn(__fmul_rn(qx0, px), __fmul_rn(qx1, py)),
                    __fmul_rn(qx2, pz));
                const float d2 = __fadd_rn(
                    __fsub_rn(qn, __fmul_rn(2.0f, dot)), sn);
                insert3_stable(d2, s, b0, b1, b2, i0, i1, i2);
            }

            // weights from direct-diff norm (reference math), gather flow
            const float ax = sx[i0], ay = sx[S_PTS + i0], az = sx[2 * S_PTS + i0];
            const float bx = sx[i1], by = sx[S_PTS + i1], bz = sx[2 * S_PTS + i1];
            const float cx = sx[i2], cy = sx[S_PTS + i2], cz = sx[2 * S_PTS + i2];

            float dx, dy, dz;
            dx = ax - qx0; dy = ay - qx1; dz = az - qx2;
            const float dist0 = fmaxf(sqrtf(dx * dx + dy * dy + dz * dz), 1e-10f);
            dx = bx - qx0; dy = by - qx1; dz = bz - qx2;
            const float dist1 = fmaxf(sqrtf(dx * dx + dy * dy + dz * dz), 1e-10f);
            dx = cx - qx0; dy = cy - qx1; dz = cz - qx2;
            const float dist2 = fmaxf(sqrtf(dx * dx + dy * dy + dz * dz), 1e-10f);

            const float inv0 = 1.0f / dist0;
            const float inv1 = 1.0f / dist1;
            const float inv2 = 1.0f / dist2;
            const float wsum = (inv0 + inv1) + inv2;
            const float w0 = inv0 / wsum;
            const float w1 = inv1 / wsum;
            const float w2 = inv2 / wsum;

            const float* fl = sparse_flow + (size_t)b * 3 * S_PTS;
            float* ob = out + (size_t)b * 3 * N;
            #pragma unroll
            for (int c = 0; c < 3; ++c) {
                const float f0 = fl[c * S_PTS + i0];
                const float f1 = fl[c * S_PTS + i1];
                const float f2 = fl[c * S_PTS + i2];
                ob[c * N + n] = (w0 * f0 + w1 * f1) + w2 * f2;
            }
        }
    }
#undef SCREEN_APPEND
#undef MERGE_BOUND
}

extern "C" void kernel_launch(void* const* d_in, const int* in_sizes, int n_in,
                              void* d_out, int out_size, void* d_ws, size_t ws_size,
                              hipStream_t stream)
{
    const float* xyz         = (const float*)d_in[0];
    const float* sparse_xyz  = (const float*)d_in[1];
    const float* sparse_flow = (const float*)d_in[2];
    float* out = (float*)d_out;

    const int B = in_sizes[1] / (3 * S_PTS);          // 2
    const int N = in_sizes[0] / (3 * B);              // 16384
    const int blocks_per_batch = (N + QPB - 1) / QPB; // 1024

    dim3 grid(B * blocks_per_batch);                  // 2048 blocks
    dim3 block(256);
    upsample_flow_knn3<<<grid, block, 0, stream>>>(
        xyz, sparse_xyz, sparse_flow, out, N, blocks_per_batch);
}